// Round 7
// baseline (1005.282 us; speedup 1.0000x reference)
//
#include <hip/hip_runtime.h>
#include <hip/hip_cooperative_groups.h>

namespace cg = cooperative_groups;

// MPNN regression. R7: single cooperative mega-kernel (10 grid.sync phases)
// replacing 12 dispatches. Rationale: R3-R6 totals pinned at ~340 us across 4
// structurally different GEMMs, and profiled GEMM dur (50 us) is K-independent
// -> fixed per-dispatch cost (launch gaps / profiler cold-cache), not kernel
// time. Fallback multi-launch path kept in case cooperative launch fails.

typedef _Float16 half8 __attribute__((ext_vector_type(8)));
typedef float float4v __attribute__((ext_vector_type(4)));

#define ASYNC_COPY16(gptr, lptr)                                              \
    __builtin_amdgcn_global_load_lds(                                         \
        (const __attribute__((address_space(1))) void*)(gptr),                \
        (__attribute__((address_space(3))) void*)(lptr), 16, 0, 0)

struct Params {
    const float* x; const int* eidx;
    const float* W_in; const float* b_in;
    const float* msg_W; const float* msg_b;
    const float* upd_W; const float* upd_b;
    const float* W_out; const float* b_out;
    float* out;
    _Float16 *xb, *B0, *B1, *B2, *WinT, *msgT, *updT;
    int *deg, *offs, *cursor, *srcs;
    int M, E;
};

union SMem {
    struct { _Float16 As[4096]; _Float16 Bs[4096]; } g;  // 16 KB
    float tp[32][33];
    int part[256];
};

// ---------- GEMM tile: C[bm:bm+64, bn:bn+64] = relu(A1@W1 [+A2@W2] + bias) ----
__device__ __forceinline__ void gemm_tile(SMem& sm, int bm, int bn,
    const _Float16* __restrict__ A1, const _Float16* __restrict__ W1t, int ldw1, int K1,
    const _Float16* __restrict__ A2, const _Float16* __restrict__ W2t, int ldw2, int K2,
    const float* __restrict__ bias, _Float16* __restrict__ C, int M, int do_relu)
{
    const int tid = threadIdx.x;
    const int wave = tid >> 6, lane = tid & 63;
    const int wr = (wave >> 1) * 32, wc = (wave & 1) * 32;
    const int m16 = lane & 15, quad = lane >> 4;
    float4v acc[2][2] = {};
    int arow = bm + lane; if (arow >= M) arow = M - 1;
    const int brow = bn + lane;

    for (int pass = 0; pass < 2; ++pass) {
        const _Float16* A  = pass ? A2 : A1;
        const _Float16* Wt = pass ? W2t : W1t;
        const int ldw = pass ? ldw2 : ldw1;
        const int K   = pass ? K2 : K1;
        if (A == nullptr) continue;
        for (int k0 = 0; k0 < K; k0 += 64) {
            #pragma unroll
            for (int t = 0; t < 2; ++t) {
                const int ch = t * 4 + wave;  // LDS dest = uniform base + lane*16
                ASYNC_COPY16(A + (size_t)arow * K + k0 + ch * 8,
                             (char*)sm.g.As + ch * 1024);
                ASYNC_COPY16(Wt + (size_t)brow * ldw + k0 + ch * 8,
                             (char*)sm.g.Bs + ch * 1024);
            }
            __syncthreads();
            #pragma unroll
            for (int c = 0; c < 2; ++c) {
                half8 af[2], bf[2];
                #pragma unroll
                for (int i = 0; i < 2; ++i)
                    af[i] = *(const half8*)
                        &sm.g.As[((c * 4 + quad) * 64 + wr + i * 16 + m16) * 8];
                #pragma unroll
                for (int j = 0; j < 2; ++j)
                    bf[j] = *(const half8*)
                        &sm.g.Bs[((c * 4 + quad) * 64 + wc + j * 16 + m16) * 8];
                #pragma unroll
                for (int i = 0; i < 2; ++i)
                    #pragma unroll
                    for (int j = 0; j < 2; ++j)
                        acc[i][j] = __builtin_amdgcn_mfma_f32_16x16x32_f16(
                            af[i], bf[j], acc[i][j], 0, 0, 0);
            }
            __syncthreads();
        }
    }
    #pragma unroll
    for (int i = 0; i < 2; ++i)
        #pragma unroll
        for (int rg = 0; rg < 4; ++rg) {
            const int row = bm + wr + i * 16 + quad * 4 + rg;
            if (row >= M) continue;
            #pragma unroll
            for (int j = 0; j < 2; ++j) {
                float v = acc[i][j][rg] + bias[bn + wc + j * 16 + m16];
                if (do_relu) v = fmaxf(v, 0.f);
                C[(size_t)row * 512 + bn + wc + j * 16 + m16] = (_Float16)v;
            }
        }
}

// which: 0=in, 1=msg0, 2=upd0, 3=msg1, 4=upd1
__device__ __forceinline__ void gemm_select(const Params& p, int which,
                                            int mt, int pn, SMem& sm)
{
    const int bm = mt * 64, bn = pn * 64;
    switch (which) {
    case 0: gemm_tile(sm, bm, bn, p.xb, p.WinT, 256, 256,
                      nullptr, nullptr, 0, 0, p.b_in, p.B0, p.M, 1); break;
    case 1: gemm_tile(sm, bm, bn, p.B0, p.msgT, 512, 512,
                      nullptr, nullptr, 0, 0, p.msg_b, p.B1, p.M, 1); break;
    case 2: gemm_tile(sm, bm, bn, p.B0, p.updT, 1024, 512,
                      p.B2, p.updT + 512, 1024, 512, p.upd_b, p.B1, p.M, 1); break;
    case 3: gemm_tile(sm, bm, bn, p.B1, p.msgT + 512 * 512, 512, 512,
                      nullptr, nullptr, 0, 0, p.msg_b + 512, p.B0, p.M, 1); break;
    case 4: gemm_tile(sm, bm, bn, p.B1, p.updT + 512 * 1024, 1024, 512,
                      p.B2, p.updT + 512 * 1024 + 512, 1024, 512,
                      p.upd_b + 512, p.B0, p.M, 1); break;
    }
}

// ---------- prep unit: 5 weight transposes / x cast / deg zero ----------
__device__ __forceinline__ void prep_unit(const Params& p, int b, SMem& sm)
{
    const int tid = threadIdx.x;
    const int n4 = p.M * 64;               // M*256/4
    const int castU = (n4 + 255) >> 8;
    if (b < 1664) {
        const float* src; _Float16* dst; int R; int tb;
        if (b < 128)       { src = p.W_in;             dst = p.WinT;             R = 256;  tb = b; }
        else if (b < 384)  { src = p.msg_W;            dst = p.msgT;             R = 512;  tb = b - 128; }
        else if (b < 640)  { src = p.msg_W + 512*512;  dst = p.msgT + 512*512;   R = 512;  tb = b - 384; }
        else if (b < 1152) { src = p.upd_W;            dst = p.updT;             R = 1024; tb = b - 640; }
        else               { src = p.upd_W + 1024*512; dst = p.updT + 512*1024;  R = 1024; tb = b - 1152; }
        const int rtiles = R >> 5;
        const int r0 = (tb % rtiles) * 32, c0 = (tb / rtiles) * 32;
        const int tx = tid & 31, ty = tid >> 5;
        #pragma unroll
        for (int i = 0; i < 32; i += 8)
            sm.tp[ty + i][tx] = src[(size_t)(r0 + ty + i) * 512 + c0 + tx];
        __syncthreads();
        #pragma unroll
        for (int i = 0; i < 32; i += 8)
            dst[(size_t)(c0 + ty + i) * R + r0 + tx] = (_Float16)sm.tp[tx][ty + i];
        __syncthreads();   // before grid-stride reuse of sm.tp
    } else if (b < 1664 + castU) {
        const int i = (b - 1664) * 256 + tid;
        if (i < n4) {
            const float4 v = *(const float4*)(p.x + (size_t)i * 4);
            ushort4 s;
            union { _Float16 h; unsigned short u; } cv;
            cv.h = (_Float16)v.x; s.x = cv.u;
            cv.h = (_Float16)v.y; s.y = cv.u;
            cv.h = (_Float16)v.z; s.z = cv.u;
            cv.h = (_Float16)v.w; s.w = cv.u;
            *(ushort4*)((unsigned short*)p.xb + (size_t)i * 4) = s;
        }
    } else {
        const int zi = (b - 1664 - castU) * 256 + tid;
        if (zi < p.M) p.deg[zi] = 0;
    }
}

__device__ __forceinline__ void scan_block(const Params& p, SMem& sm)
{
    const int tid = threadIdx.x;
    const int n = p.M;
    const int chunk = (n + 255) >> 8;
    const int base = tid * chunk;
    int sum = 0;
    for (int i = 0; i < chunk; ++i) { int idx = base + i; if (idx < n) sum += p.deg[idx]; }
    sm.part[tid] = sum;
    __syncthreads();
    for (int off = 1; off < 256; off <<= 1) {
        int v = (tid >= off) ? sm.part[tid - off] : 0;
        __syncthreads();
        sm.part[tid] += v;
        __syncthreads();
    }
    int run = (tid == 0) ? 0 : sm.part[tid - 1];
    for (int i = 0; i < chunk; ++i) {
        int idx = base + i;
        if (idx < n) { p.offs[idx] = run; p.cursor[idx] = run; run += p.deg[idx]; }
    }
    if (tid == 255) p.offs[n] = sm.part[255];
}

// ---------- aggregation unit: u -> (q = u&3, nodegroup = u>>2) ----------
__device__ __forceinline__ void agg_unit(const Params& p, int u,
    const _Float16* __restrict__ hmr, _Float16* __restrict__ ag)
{
    const int node = (u >> 2) * 16 + (threadIdx.x >> 4);
    if (node >= p.M) return;
    const int c8 = (u & 3) * 128 + (threadIdx.x & 15) * 8;
    const int beg = p.offs[node], end = p.offs[node + 1];
    float a[8] = {};
    int j = beg;
    for (; j + 1 < end; j += 2) {
        const half8 v0 = *(const half8*)(hmr + (size_t)p.srcs[j]     * 512 + c8);
        const half8 v1 = *(const half8*)(hmr + (size_t)p.srcs[j + 1] * 512 + c8);
        #pragma unroll
        for (int i = 0; i < 8; ++i) a[i] += (float)v0[i] + (float)v1[i];
    }
    if (j < end) {
        const half8 v = *(const half8*)(hmr + (size_t)p.srcs[j] * 512 + c8);
        #pragma unroll
        for (int i = 0; i < 8; ++i) a[i] += (float)v[i];
    }
    half8 o;
    #pragma unroll
    for (int i = 0; i < 8; ++i) o[i] = (_Float16)a[i];
    *(half8*)(ag + (size_t)node * 512 + c8) = o;
}

__device__ __forceinline__ void outdot_unit(const Params& p, int gid)
{
    const int node = gid >> 6, lane = gid & 63;
    if (node >= p.M) return;
    const half8 hv = *(const half8*)(p.B0 + (size_t)node * 512 + lane * 8);
    const float4 w0 = *(const float4*)(p.W_out + lane * 8);
    const float4 w1 = *(const float4*)(p.W_out + lane * 8 + 4);
    float s = (float)hv[0] * w0.x + (float)hv[1] * w0.y
            + (float)hv[2] * w0.z + (float)hv[3] * w0.w
            + (float)hv[4] * w1.x + (float)hv[5] * w1.y
            + (float)hv[6] * w1.z + (float)hv[7] * w1.w;
    #pragma unroll
    for (int off = 32; off > 0; off >>= 1)
        s += __shfl_down(s, off);
    if (lane == 0) p.out[node] = s + p.b_out[0];
}

// ================= cooperative mega-kernel =================
__global__ __launch_bounds__(256) void mpnn_fused(Params p)
{
    __shared__ SMem sm;
    cg::grid_group grid = cg::this_grid();
    const int tid = threadIdx.x;
    const int G = gridDim.x;
    const int M = p.M, E = p.E;
    const int Mtiles = (M + 63) >> 6;
    const int gemmU = Mtiles * 8;
    const int n4 = M * 64;
    const int castU = (n4 + 255) >> 8;
    const int zeroU = (M + 255) >> 8;

    // A: weight transposes + x cast + deg zero
    for (int b = blockIdx.x; b < 1664 + castU + zeroU; b += G)
        prep_unit(p, b, sm);
    grid.sync();

    // B: degree count
    for (int e = blockIdx.x * 256 + tid; e < E; e += G * 256)
        atomicAdd(&p.deg[p.eidx[E + e]], 1);
    grid.sync();

    // C: exclusive scan (block 0)
    if (blockIdx.x == 0) scan_block(p, sm);
    grid.sync();

    // D: CSR fill  ||  in-GEMM h0 = relu(x@W_in+b)  (independent)
    {
        const int fillU = (E + 255) >> 8;
        for (int u = blockIdx.x; u < fillU + gemmU; u += G) {
            if (u < fillU) {
                const int e = u * 256 + tid;
                if (e < E) {
                    const int pos = atomicAdd(&p.cursor[p.eidx[E + e]], 1);
                    p.srcs[pos] = p.eidx[e];
                }
            } else {
                const int t2 = u - fillU;
                gemm_select(p, 0, t2 >> 3, t2 & 7, sm);
            }
        }
    }
    grid.sync();

    const int aggU = ((M + 15) >> 4) * 4;

    // E: msg l0  (B0 -> B1)
    for (int u = blockIdx.x; u < gemmU; u += G) gemm_select(p, 1, u >> 3, u & 7, sm);
    grid.sync();
    // F: aggregate l0  (B1 -> B2)
    for (int u = blockIdx.x; u < aggU; u += G) agg_unit(p, u, p.B1, p.B2);
    grid.sync();
    // G: upd l0  (B0,B2 -> B1)
    for (int u = blockIdx.x; u < gemmU; u += G) gemm_select(p, 2, u >> 3, u & 7, sm);
    grid.sync();
    // H: msg l1  (B1 -> B0)
    for (int u = blockIdx.x; u < gemmU; u += G) gemm_select(p, 3, u >> 3, u & 7, sm);
    grid.sync();
    // I: aggregate l1  (B0 -> B2)
    for (int u = blockIdx.x; u < aggU; u += G) agg_unit(p, u, p.B0, p.B2);
    grid.sync();
    // J: upd l1  (B1,B2 -> B0)
    for (int u = blockIdx.x; u < gemmU; u += G) gemm_select(p, 4, u >> 3, u & 7, sm);
    grid.sync();
    // K: out = B0 @ W_out + b_out
    for (int gid = blockIdx.x * 256 + tid; gid < M * 64; gid += G * 256)
        outdot_unit(p, gid);
}

// ================= fallback (non-cooperative) kernels =================
__global__ __launch_bounds__(256) void k_prep(Params p)
{ __shared__ SMem sm; prep_unit(p, blockIdx.x, sm); }

__global__ __launch_bounds__(256) void k_count(Params p)
{ const int e = blockIdx.x * 256 + threadIdx.x;
  if (e < p.E) atomicAdd(&p.deg[p.eidx[p.E + e]], 1); }

__global__ __launch_bounds__(256) void k_scan(Params p)
{ __shared__ SMem sm; scan_block(p, sm); }

__global__ __launch_bounds__(256) void k_fill(Params p)
{ const int e = blockIdx.x * 256 + threadIdx.x;
  if (e < p.E) { const int pos = atomicAdd(&p.cursor[p.eidx[p.E + e]], 1);
                 p.srcs[pos] = p.eidx[e]; } }

__global__ __launch_bounds__(256) void k_gemm(Params p, int which)
{ __shared__ SMem sm; gemm_select(p, which, blockIdx.x, blockIdx.y, sm); }

__global__ __launch_bounds__(256) void k_agg(Params p, int which)
{ const int u = blockIdx.x * 4 + blockIdx.y;
  if (which == 0) agg_unit(p, u, p.B1, p.B2);
  else            agg_unit(p, u, p.B0, p.B2); }

__global__ __launch_bounds__(256) void k_out(Params p)
{ outdot_unit(p, blockIdx.x * 256 + threadIdx.x); }

extern "C" void kernel_launch(void* const* d_in, const int* in_sizes, int n_in,
                              void* d_out, int out_size, void* d_ws, size_t ws_size,
                              hipStream_t stream)
{
    Params P;
    P.x     = (const float*)d_in[0];
    P.eidx  = (const int*)  d_in[1];
    P.W_in  = (const float*)d_in[2];
    P.b_in  = (const float*)d_in[3];
    P.msg_W = (const float*)d_in[4];
    P.msg_b = (const float*)d_in[5];
    P.upd_W = (const float*)d_in[6];
    P.upd_b = (const float*)d_in[7];
    P.W_out = (const float*)d_in[8];
    P.b_out = (const float*)d_in[9];
    P.out   = (float*)d_out;

    const int IN = 256, H = 512;
    P.M = in_sizes[0] / IN;   // 10000
    P.E = in_sizes[1] / 2;    // 160000

    _Float16* w = (_Float16*)d_ws;
    P.xb   = w; w += (size_t)P.M * IN;
    P.B0   = w; w += (size_t)P.M * H;
    P.B1   = w; w += (size_t)P.M * H;
    P.B2   = w; w += (size_t)P.M * H;
    P.WinT = w; w += (size_t)H * IN;
    P.msgT = w; w += (size_t)2 * H * H;
    P.updT = w; w += (size_t)2 * H * 2 * H;
    int* wi = (int*)w;
    P.deg    = wi; wi += P.M;
    P.offs   = wi; wi += P.M + 1;
    P.cursor = wi; wi += P.M;
    P.srcs   = wi;

    const int Mtiles = (P.M + 63) / 64;
    const int n4 = P.M * 64;
    const int castU = (n4 + 255) / 256;
    const int zeroU = (P.M + 255) / 256;

    // cooperative launch, clamped to guaranteed co-residency
    int maxPerCU = 0;
    hipError_t oe = hipOccupancyMaxActiveBlocksPerMultiprocessor(
        &maxPerCU, mpnn_fused, 256, 0);
    int G = (oe == hipSuccess ? maxPerCU : 0) * 256;   // 256 CUs on MI355X
    if (G > 1024) G = 1024;
    hipError_t err = hipErrorUnknown;
    if (G >= 256) {
        void* args[] = { (void*)&P };
        err = hipLaunchCooperativeKernel((void*)mpnn_fused,
                                         dim3(G), dim3(256), args, 0, stream);
    }
    if (err != hipSuccess) {
        // fallback: R6-equivalent multi-launch pipeline
        const dim3 blk(256);
        k_prep <<<dim3(1664 + castU + zeroU), blk, 0, stream>>>(P);
        k_count<<<dim3((P.E + 255) / 256),    blk, 0, stream>>>(P);
        k_scan <<<dim3(1),                    blk, 0, stream>>>(P);
        k_fill <<<dim3((P.E + 255) / 256),    blk, 0, stream>>>(P);
        k_gemm <<<dim3(Mtiles, 8), blk, 0, stream>>>(P, 0);
        k_gemm <<<dim3(Mtiles, 8), blk, 0, stream>>>(P, 1);
        k_agg  <<<dim3((P.M + 15) / 16, 4), blk, 0, stream>>>(P, 0);
        k_gemm <<<dim3(Mtiles, 8), blk, 0, stream>>>(P, 2);
        k_gemm <<<dim3(Mtiles, 8), blk, 0, stream>>>(P, 3);
        k_agg  <<<dim3((P.M + 15) / 16, 4), blk, 0, stream>>>(P, 1);
        k_gemm <<<dim3(Mtiles, 8), blk, 0, stream>>>(P, 4);
        k_out  <<<dim3((P.M * 64 + 255) / 256), blk, 0, stream>>>(P);
    }
}

// Round 8
// 262.626 us; speedup vs baseline: 3.8278x; 3.8278x over previous
//
#include <hip/hip_runtime.h>

// MPNN regression. R8: revert R7 mega-kernel (grid.sync too costly on 8 XCDs).
// Key fix from R7's post-mortem: R3-R6 GEMMs staged A/B with row-per-lane
// global_load_lds = 64 cache lines per instruction (16B used per line) ->
// transaction-rate bound ~50us invariant. Now all GEMM inputs live in a packed
// tile format P[mt][kt][ch][row][8] == the LDS image, so staging is lane-linear
// contiguous (lane L <- base + L*16). ds_read indexing unchanged (0 conflicts).

typedef _Float16 half8 __attribute__((ext_vector_type(8)));
typedef float float4v __attribute__((ext_vector_type(4)));

#define ASYNC_COPY16(gptr, lptr)                                              \
    __builtin_amdgcn_global_load_lds(                                         \
        (const __attribute__((address_space(1))) void*)(gptr),                \
        (__attribute__((address_space(3))) void*)(lptr), 16, 0, 0)

// packed addr (halfs) for element (m,k) of a [*,K] matrix, KT = K/64:
//   ((m/64*KT + k/64)*8 + (k%64)/8)*512 + (m%64)*8 + k%8

// ---------------- fp16 MFMA GEMM, packed inputs ----------------
// C = relu(A1@W1 [+ A2@W2] + bias). A1/A2/Wt packed. Wt is W^T [512, K].
// Block 64x64, 4 waves of 32x32, BK=64. packC: 1 = packed C, 0 = row-major C.
__global__ __launch_bounds__(256) void gemm_f16(
    const _Float16* __restrict__ A1, int KT1,
    const _Float16* __restrict__ A2, int KT2,
    const _Float16* __restrict__ Wt, int KTw, int ktw2,
    const float* __restrict__ bias, _Float16* __restrict__ C,
    int M, int Mtiles, int packC, int do_relu)
{
    __shared__ _Float16 As[4096];   // [ch 0..7][row 0..63][8]  8 KB
    __shared__ _Float16 Bs[4096];

    const int tid  = threadIdx.x;
    const int wave = tid >> 6, lane = tid & 63;

    // swizzle: 8 pn-panels of one mt land on consecutive ids == cxcd (mod 8)
    const int id = blockIdx.x;
    const int cxcd = id & 7, j = id >> 3;
    const int mt = cxcd + 8 * (j >> 3);
    if (mt >= Mtiles) return;
    const int pn = j & 7;
    const int bm = mt * 64, bn = pn * 64;

    const int wr = (wave >> 1) * 32, wc = (wave & 1) * 32;
    const int m16 = lane & 15, quad = lane >> 4;

    float4v acc[2][2] = {};
    float bv[2];
    #pragma unroll
    for (int jj = 0; jj < 2; ++jj) bv[jj] = bias[bn + wc + jj * 16 + m16];

    for (int pass = 0; pass < 2; ++pass) {
        const _Float16* __restrict__ A = pass ? A2 : A1;
        if (A == nullptr) continue;
        const int KTa  = pass ? KT2 : KT1;
        const int ktw0 = pass ? ktw2 : 0;

        for (int kt = 0; kt < KTa; ++kt) {
            const _Float16* Ab = A  + (size_t)(mt * KTa + kt) * 4096;
            const _Float16* Wb = Wt + (size_t)(pn * KTw + ktw0 + kt) * 4096;
            #pragma unroll
            for (int t = 0; t < 2; ++t) {
                const int q = t * 4 + wave;      // instr 0..7, 1 KB each
                // src per-lane contiguous; LDS dest = uniform base + lane*16
                ASYNC_COPY16(Ab + q * 512 + lane * 8, (char*)As + q * 1024);
                ASYNC_COPY16(Wb + q * 512 + lane * 8, (char*)Bs + q * 1024);
            }
            __syncthreads();
            #pragma unroll
            for (int c = 0; c < 2; ++c) {
                half8 af[2], bf[2];
                #pragma unroll
                for (int i = 0; i < 2; ++i)
                    af[i] = *(const half8*)
                        &As[((c * 4 + quad) * 64 + wr + i * 16 + m16) * 8];
                #pragma unroll
                for (int j2 = 0; j2 < 2; ++j2)
                    bf[j2] = *(const half8*)
                        &Bs[((c * 4 + quad) * 64 + wc + j2 * 16 + m16) * 8];
                #pragma unroll
                for (int i = 0; i < 2; ++i)
                    #pragma unroll
                    for (int j2 = 0; j2 < 2; ++j2)
                        acc[i][j2] = __builtin_amdgcn_mfma_f32_16x16x32_f16(
                            af[i], bf[j2], acc[i][j2], 0, 0, 0);
            }
            __syncthreads();
        }
    }

    // epilogue: D layout col=lane&15, row=quad*4+reg
    #pragma unroll
    for (int i = 0; i < 2; ++i)
        #pragma unroll
        for (int rg = 0; rg < 4; ++rg) {
            const int r2 = wr + i * 16 + quad * 4 + rg;   // row within tile
            const int row = bm + r2;
            if (row >= M) continue;
            #pragma unroll
            for (int j2 = 0; j2 < 2; ++j2) {
                float v = acc[i][j2][rg] + bv[j2];
                if (do_relu) v = fmaxf(v, 0.f);
                const int coff = wc + j2 * 16 + m16;      // col within tile
                if (packC) {
                    // C is [*,512] packed: kt2 = pn, KT = 8
                    C[(size_t)((mt * 8 + pn) * 8 + (coff >> 3)) * 512
                      + r2 * 8 + (coff & 7)] = (_Float16)v;
                } else {
                    C[(size_t)row * 512 + bn + coff] = (_Float16)v;
                }
            }
        }
}

// ---------------- fused prep: weight transpose->packed + x cast + deg zero ---
// Weights: src f32 [R,512]; dst = packed W^T [512 rows(n), R cols(k)], KT=R/64.
__global__ __launch_bounds__(256) void prep(
    const float* __restrict__ W_in,  _Float16* __restrict__ WinT,
    const float* __restrict__ msg_W, _Float16* __restrict__ msgT,
    const float* __restrict__ upd_W, _Float16* __restrict__ updT,
    const float* __restrict__ x,     _Float16* __restrict__ xb,
    int* __restrict__ deg, int n4, int M)
{
    const int b = blockIdx.x;
    const int tid = threadIdx.x;
    const int castU = (n4 + 255) >> 8;
    if (b < 1664) {
        const float* src; _Float16* dst; int R; int tb;
        if (b < 128)       { src = W_in;               dst = WinT;              R = 256;  tb = b; }
        else if (b < 384)  { src = msg_W;              dst = msgT;              R = 512;  tb = b - 128; }
        else if (b < 640)  { src = msg_W + 512 * 512;  dst = msgT + 512 * 512;  R = 512;  tb = b - 384; }
        else if (b < 1152) { src = upd_W;              dst = updT;              R = 1024; tb = b - 640; }
        else               { src = upd_W + 1024 * 512; dst = updT + 512 * 1024; R = 1024; tb = b - 1152; }
        const int rtiles = R >> 5;
        const int r0 = (tb % rtiles) * 32, c0 = (tb / rtiles) * 32;
        const int KT = R >> 6;
        __shared__ float t[32][33];
        const int tx = tid & 31, ty = tid >> 5;
        #pragma unroll
        for (int i = 0; i < 32; i += 8)
            t[ty + i][tx] = src[(size_t)(r0 + ty + i) * 512 + c0 + tx];
        __syncthreads();
        #pragma unroll
        for (int i = 0; i < 32; i += 8) {
            const int n = c0 + ty + i;   // packed row (0..511)
            const int k = r0 + tx;       // packed col (0..R-1)
            dst[(size_t)(((n >> 6) * KT + (k >> 6)) * 8 + ((k >> 3) & 7)) * 512
                + (n & 63) * 8 + (k & 7)] = (_Float16)t[tx][ty + i];
        }
    } else if (b < 1664 + castU) {
        const int i = (b - 1664) * 256 + tid;
        if (i < n4) {
            const float4 v = *(const float4*)(x + (size_t)i * 4);
            ushort4 s;
            union { _Float16 h; unsigned short u; } cv;
            cv.h = (_Float16)v.x; s.x = cv.u;
            cv.h = (_Float16)v.y; s.y = cv.u;
            cv.h = (_Float16)v.z; s.z = cv.u;
            cv.h = (_Float16)v.w; s.w = cv.u;
            const int f = i * 4;                 // flat half idx, [M,256]
            const int m = f >> 8, k = f & 255;   // k%8 in {0,4}
            *(ushort4*)((unsigned short*)xb
                + (size_t)(((m >> 6) * 4 + (k >> 6)) * 8 + ((k >> 3) & 7)) * 512
                + (m & 63) * 8 + (k & 7)) = s;
        }
    } else {
        const int zi = (b - 1664 - castU) * 256 + tid;
        if (zi < M) deg[zi] = 0;
    }
}

// ---------------- CSR build ----------------
__global__ __launch_bounds__(256) void count_deg(
    const int* __restrict__ eidx, int* __restrict__ deg, int E)
{
    const int e = blockIdx.x * 256 + threadIdx.x;
    if (e < E) atomicAdd(&deg[eidx[E + e]], 1);
}

__global__ __launch_bounds__(256) void scan_offsets(
    const int* __restrict__ deg, int* __restrict__ offs,
    int* __restrict__ cursor, int n)
{
    __shared__ int part[256];
    const int tid = threadIdx.x;
    const int chunk = (n + 255) / 256;
    const int base = tid * chunk;
    int sum = 0;
    for (int i = 0; i < chunk; ++i) {
        const int idx = base + i;
        if (idx < n) sum += deg[idx];
    }
    part[tid] = sum;
    __syncthreads();
    for (int off = 1; off < 256; off <<= 1) {
        const int v = (tid >= off) ? part[tid - off] : 0;
        __syncthreads();
        part[tid] += v;
        __syncthreads();
    }
    int run = (tid == 0) ? 0 : part[tid - 1];
    for (int i = 0; i < chunk; ++i) {
        const int idx = base + i;
        if (idx < n) { offs[idx] = run; cursor[idx] = run; run += deg[idx]; }
    }
    if (tid == 255) offs[n] = part[255];
}

__global__ __launch_bounds__(256) void fill_csr(
    const int* __restrict__ eidx, int* __restrict__ cursor,
    int* __restrict__ srcs, int E)
{
    const int e = blockIdx.x * 256 + threadIdx.x;
    if (e < E) {
        const int pos = atomicAdd(&cursor[eidx[E + e]], 1);
        srcs[pos] = eidx[e];
    }
}

// ------- aggregation: hmr row-major in, ag PACKED out. Column-quartered. -----
__global__ __launch_bounds__(256) void aggregate_f16(
    const _Float16* __restrict__ hmr, const int* __restrict__ offs,
    const int* __restrict__ srcs, _Float16* __restrict__ ag, int n)
{
    const int l16  = threadIdx.x & 15;
    const int node = blockIdx.x * 16 + (threadIdx.x >> 4);
    if (node >= n) return;
    const int c8 = blockIdx.y * 128 + l16 * 8;
    const int beg = offs[node], end = offs[node + 1];
    float a[8] = {};
    int j = beg;
    for (; j + 1 < end; j += 2) {
        const half8 v0 = *(const half8*)(hmr + (size_t)srcs[j]     * 512 + c8);
        const half8 v1 = *(const half8*)(hmr + (size_t)srcs[j + 1] * 512 + c8);
        #pragma unroll
        for (int i = 0; i < 8; ++i) a[i] += (float)v0[i] + (float)v1[i];
    }
    if (j < end) {
        const half8 v = *(const half8*)(hmr + (size_t)srcs[j] * 512 + c8);
        #pragma unroll
        for (int i = 0; i < 8; ++i) a[i] += (float)v[i];
    }
    half8 o;
    #pragma unroll
    for (int i = 0; i < 8; ++i) o[i] = (_Float16)a[i];
    // packed store: one 16B chunk
    *(half8*)(ag + (size_t)(((node >> 6) * 8 + (c8 >> 6)) * 8 + ((c8 >> 3) & 7)) * 512
              + (node & 63) * 8) = o;
}

// ---------------- epilogue dot: out = h(packed) @ W_out + b_out --------------
__global__ __launch_bounds__(256) void out_dot(
    const _Float16* __restrict__ h, const float* __restrict__ Wout,
    const float* __restrict__ bout, float* __restrict__ out, int M)
{
    const int gid = blockIdx.x * 256 + threadIdx.x;
    const int node = gid >> 6;
    const int lane = gid & 63;
    if (node >= M) return;
    const half8 hv = *(const half8*)(h
        + (size_t)(((node >> 6) * 8 + (lane >> 3)) * 8 + (lane & 7)) * 512
        + (node & 63) * 8);
    const float4 w0 = *(const float4*)(Wout + lane * 8);
    const float4 w1 = *(const float4*)(Wout + lane * 8 + 4);
    float s = (float)hv[0] * w0.x + (float)hv[1] * w0.y
            + (float)hv[2] * w0.z + (float)hv[3] * w0.w
            + (float)hv[4] * w1.x + (float)hv[5] * w1.y
            + (float)hv[6] * w1.z + (float)hv[7] * w1.w;
    #pragma unroll
    for (int off = 32; off > 0; off >>= 1)
        s += __shfl_down(s, off);
    if (lane == 0) out[node] = s + bout[0];
}

extern "C" void kernel_launch(void* const* d_in, const int* in_sizes, int n_in,
                              void* d_out, int out_size, void* d_ws, size_t ws_size,
                              hipStream_t stream)
{
    const float* x     = (const float*)d_in[0];
    const int*   eidx  = (const int*)  d_in[1];
    const float* W_in  = (const float*)d_in[2];
    const float* b_in  = (const float*)d_in[3];
    const float* msg_W = (const float*)d_in[4];
    const float* msg_b = (const float*)d_in[5];
    const float* upd_W = (const float*)d_in[6];
    const float* upd_b = (const float*)d_in[7];
    const float* W_out = (const float*)d_in[8];
    const float* b_out = (const float*)d_in[9];

    const int IN = 256, H = 512;
    const int M = in_sizes[0] / IN;   // 10000
    const int E = in_sizes[1] / 2;    // 160000
    const int Mtiles = (M + 63) / 64;
    const size_t Mt64 = (size_t)Mtiles * 64;

    _Float16* xb   = (_Float16*)d_ws;           // packed [Mt64, 256]
    _Float16* B0   = xb + Mt64 * IN;            // packed or row-major [Mt64,512]
    _Float16* B1   = B0 + Mt64 * H;
    _Float16* B2   = B1 + Mt64 * H;             // packed aggr
    _Float16* WinT = B2 + Mt64 * H;             // packed [512,256]
    _Float16* msgT = WinT + (size_t)H * IN;     // packed [2][512,512]
    _Float16* updT = msgT + (size_t)2 * H * H;  // packed [2][512,1024]
    int* deg    = (int*)(updT + (size_t)2 * H * 2 * H);
    int* offs   = deg + M;
    int* cursor = offs + M + 1;
    int* srcs   = cursor + M;

    const dim3 blk(256);
    const dim3 gemmGrid(((Mtiles + 7) / 8) * 64);
    const dim3 edgeGrid((E + 255) / 256);
    const dim3 aggrGrid((M + 15) / 16, 4);

    const int n4 = M * IN / 4;
    const int castU = (n4 + 255) / 256;
    const int zeroU = (M + 255) / 256;
    prep<<<dim3(1664 + castU + zeroU), blk, 0, stream>>>(
        W_in, WinT, msg_W, msgT, upd_W, updT, x, xb, deg, n4, M);

    count_deg<<<edgeGrid, blk, 0, stream>>>(eidx, deg, E);
    scan_offsets<<<dim3(1), blk, 0, stream>>>(deg, offs, cursor, M);
    fill_csr<<<edgeGrid, blk, 0, stream>>>(eidx, cursor, srcs, E);

    // h0 = relu(x @ W_in + b)        xb(packed,KT=4) -> B0 packed
    gemm_f16<<<gemmGrid, blk, 0, stream>>>(xb, 4, nullptr, 0,
                                           WinT, 4, 0, b_in, B0, M, Mtiles, 1, 1);
    // layer 0
    gemm_f16<<<gemmGrid, blk, 0, stream>>>(B0, 8, nullptr, 0,        // msg: ->B1 row-major
                                           msgT, 8, 0, msg_b, B1, M, Mtiles, 0, 1);
    aggregate_f16<<<aggrGrid, blk, 0, stream>>>(B1, offs, srcs, B2, M);
    gemm_f16<<<gemmGrid, blk, 0, stream>>>(B0, 8, B2, 8,             // upd: ->B1 packed
                                           updT, 16, 8, upd_b, B1, M, Mtiles, 1, 1);
    // layer 1
    gemm_f16<<<gemmGrid, blk, 0, stream>>>(B1, 8, nullptr, 0,        // msg: ->B0 row-major
                                           msgT + 512 * 512, 8, 0,
                                           msg_b + 512, B0, M, Mtiles, 0, 1);
    aggregate_f16<<<aggrGrid, blk, 0, stream>>>(B0, offs, srcs, B2, M);
    gemm_f16<<<gemmGrid, blk, 0, stream>>>(B1, 8, B2, 8,             // upd: ->B0 packed
                                           updT + 512 * 1024, 16, 8,
                                           upd_b + 512, B0, M, Mtiles, 1, 1);

    out_dot<<<dim3((M * 64 + 255) / 256), blk, 0, stream>>>(
        B0, W_out, b_out, (float*)d_out, M);
}